// Round 2
// baseline (1585.842 us; speedup 1.0000x reference)
//
#include <hip/hip_runtime.h>
#include <cstdint>

// FP8(e4m3 bit-pulse) -> FP16 bit-pulse converter.
// Each group: 8 input floats (0.0/1.0) -> 16 output floats (0.0/1.0).
// Memory-bound: 32B read + 64B write per group.

__global__ __launch_bounds__(256) void fp8_to_fp16_bits_kernel(
    const float4* __restrict__ in4,   // 2 float4 per group
    float4* __restrict__ out4,        // 4 float4 per group
    int n_groups)
{
    int idx = blockIdx.x * blockDim.x + threadIdx.x;
    int stride = gridDim.x * blockDim.x;
    for (int g = idx; g < n_groups; g += stride) {
        float4 a = in4[2 * g];
        float4 b = in4[2 * g + 1];

        uint32_t s  = a.x != 0.0f;
        uint32_t e3 = a.y != 0.0f;
        uint32_t e2 = a.z != 0.0f;
        uint32_t e1 = a.w != 0.0f;
        uint32_t e0 = b.x != 0.0f;
        uint32_t m2 = b.y != 0.0f;
        uint32_t m1 = b.z != 0.0f;
        uint32_t m0 = b.w != 0.0f;

        uint32_t e = (e3 << 3) | (e2 << 2) | (e1 << 1) | e0;
        uint32_t m = (m2 << 2) | (m1 << 1) | m0;

        uint32_t exp5, mant10;
        if (e) {                       // normal: exp += 8, mantissa passthrough
            exp5 = e + 8u;
            mant10 = m << 7;
        } else if (m2) {               // subnormal, lead at bit 2
            exp5 = 8u;
            mant10 = (m & 3u) << 8;    // {m1, m0, 0...}
        } else if (m1) {               // lead at bit 1
            exp5 = 7u;
            mant10 = (m & 1u) << 9;    // {m0, 0...}
        } else if (m0) {               // lead at bit 0
            exp5 = 6u;
            mant10 = 0u;
        } else {                       // zero
            exp5 = 0u;
            mant10 = 0u;
        }

        // bit 15 = sign, bits 14..10 = exp (MSB first), bits 9..0 = mantissa
        uint32_t word = (s << 15) | (exp5 << 10) | mant10;

        float o[16];
        #pragma unroll
        for (int j = 0; j < 16; ++j)
            o[j] = (float)((word >> (15 - j)) & 1u);

        float4* op = out4 + 4 * g;
        op[0] = make_float4(o[0],  o[1],  o[2],  o[3]);
        op[1] = make_float4(o[4],  o[5],  o[6],  o[7]);
        op[2] = make_float4(o[8],  o[9],  o[10], o[11]);
        op[3] = make_float4(o[12], o[13], o[14], o[15]);
    }
}

extern "C" void kernel_launch(void* const* d_in, const int* in_sizes, int n_in,
                              void* d_out, int out_size, void* d_ws, size_t ws_size,
                              hipStream_t stream)
{
    const float4* in4 = (const float4*)d_in[0];
    float4* out4 = (float4*)d_out;
    int n_groups = in_sizes[0] / 8;   // 8192*2048 = 16,777,216

    // 2048 blocks x 256 threads = 8 blocks/CU on 256 CUs (full wave occupancy);
    // grid-stride covers all groups (32 iters/thread).
    dim3 grid(2048), block(256);
    fp8_to_fp16_bits_kernel<<<grid, block, 0, stream>>>(in4, out4, n_groups);
}

// Round 3
// 1366.319 us; speedup vs baseline: 1.1607x; 1.1607x over previous
//
#include <hip/hip_runtime.h>
#include <cstdint>

// FP8(e4m3 bit-pulse) -> FP16 bit-pulse converter.
// Work-item = one output float4 (quad of bits). The 4 threads covering one
// group issue same-address input loads (merged by the coalescer); output
// stores are perfectly lane-contiguous (1 KiB per wave store instruction).

__global__ __launch_bounds__(256) void fp8_to_fp16_bits_kernel(
    const float4* __restrict__ in4,   // 2 float4 per group
    float4* __restrict__ out4,        // 4 float4 per group
    int n_out4)
{
    int idx = blockIdx.x * blockDim.x + threadIdx.x;
    int stride = gridDim.x * blockDim.x;
    for (int o = idx; o < n_out4; o += stride) {
        int g = o >> 2;               // group index
        int q = o & 3;                // which quad of the 16 output bits
        float4 a = in4[2 * g];
        float4 b = in4[2 * g + 1];

        uint32_t s  = a.x != 0.0f;
        uint32_t e3 = a.y != 0.0f;
        uint32_t e2 = a.z != 0.0f;
        uint32_t e1 = a.w != 0.0f;
        uint32_t e0 = b.x != 0.0f;
        uint32_t m2 = b.y != 0.0f;
        uint32_t m1 = b.z != 0.0f;
        uint32_t m0 = b.w != 0.0f;

        uint32_t e = (e3 << 3) | (e2 << 2) | (e1 << 1) | e0;
        uint32_t m = (m2 << 2) | (m1 << 1) | m0;

        // Branchless priority select (cndmask chains, no divergence):
        // normal: exp=e+8, mant={m2,m1,m0,0..}; subnormal: normalize by lead bit.
        uint32_t exp5  = e  ? e + 8u
                       : m2 ? 8u
                       : m1 ? 7u
                       : m0 ? 6u
                       :      0u;
        uint32_t mant10 = e  ? (m << 7)
                        : m2 ? ((m & 3u) << 8)
                        : m1 ? ((m & 1u) << 9)
                        :      0u;

        // bit 15 = sign, 14..10 = exp MSB-first, 9..0 = mantissa MSB-first
        uint32_t word = (s << 15) | (exp5 << 10) | mant10;

        int sh = 15 - 4 * q;          // MSB position of this quad
        float4 r;
        r.x = ((word >> (sh    )) & 1u) ? 1.0f : 0.0f;
        r.y = ((word >> (sh - 1)) & 1u) ? 1.0f : 0.0f;
        r.z = ((word >> (sh - 2)) & 1u) ? 1.0f : 0.0f;
        r.w = ((word >> (sh - 3)) & 1u) ? 1.0f : 0.0f;

        out4[o] = r;                  // lane-contiguous: fully coalesced
    }
}

extern "C" void kernel_launch(void* const* d_in, const int* in_sizes, int n_in,
                              void* d_out, int out_size, void* d_ws, size_t ws_size,
                              hipStream_t stream)
{
    const float4* in4 = (const float4*)d_in[0];
    float4* out4 = (float4*)d_out;
    int n_out4 = out_size / 4;        // 67,108,864 output float4

    // 2048 blocks x 256 threads = 8 blocks/CU on 256 CUs; grid-stride (128 iters).
    dim3 grid(2048), block(256);
    fp8_to_fp16_bits_kernel<<<grid, block, 0, stream>>>(in4, out4, n_out4);
}

// Round 4
// 1351.108 us; speedup vs baseline: 1.1737x; 1.0113x over previous
//
#include <hip/hip_runtime.h>
#include <cstdint>

// FP8(e4m3 bit-pulse) -> FP16 bit-pulse converter, wave-cooperative.
// Per iteration each 64-lane wave handles 64 groups:
//   - lane l loads group (base+l)'s 32 B (contiguous across lanes, no redundancy)
//   - decodes once into a 16-bit word
//   - 4 store instructions, each lane-contiguous (1 KiB/wave-store); the word
//     for the quad lane l writes in store k comes from lane 16k+(l>>2) via __shfl.

typedef float f32x4 __attribute__((ext_vector_type(4)));

__global__ __launch_bounds__(256) void fp8_to_fp16_bits_kernel(
    const f32x4* __restrict__ in4,   // 2 per group
    f32x4* __restrict__ out4,        // 4 per group
    int n_groups)                    // multiple of 64 (2^24 here)
{
    const int lane   = threadIdx.x & 63;
    const int gwave  = (int)((blockIdx.x * blockDim.x + threadIdx.x) >> 6);
    const int nwaves = (int)((gridDim.x * blockDim.x) >> 6);
    const int q    = lane & 3;       // which quad of 16 bits this lane stores
    const int sh3  = 12 - 4 * q;     // LSB position of that quad (bits sh3+3..sh3)
    const int srcb = lane >> 2;      // source-lane base for the shuffle

    for (int base = gwave * 64; base < n_groups; base += nwaves * 64) {
        const int g = base + lane;
        f32x4 a = __builtin_nontemporal_load(&in4[2 * g]);
        f32x4 b = __builtin_nontemporal_load(&in4[2 * g + 1]);

        uint32_t s  = a[0] != 0.0f;
        uint32_t e3 = a[1] != 0.0f;
        uint32_t e2 = a[2] != 0.0f;
        uint32_t e1 = a[3] != 0.0f;
        uint32_t e0 = b[0] != 0.0f;
        uint32_t m2 = b[1] != 0.0f;
        uint32_t m1 = b[2] != 0.0f;
        uint32_t m0 = b[3] != 0.0f;

        uint32_t e = (e3 << 3) | (e2 << 2) | (e1 << 1) | e0;
        uint32_t m = (m2 << 2) | (m1 << 1) | m0;

        // normal: exp=e+8, mant={m2,m1,m0,0..}; subnormal: normalize by lead bit
        uint32_t exp5 = e  ? e + 8u
                      : m2 ? 8u
                      : m1 ? 7u
                      : m0 ? 6u
                      :      0u;
        uint32_t mant = e  ? (m << 7)
                      : m2 ? ((m & 3u) << 8)
                      : m1 ? ((m & 1u) << 9)
                      :      0u;
        // bit15 = sign, 14..10 = exp MSB-first, 9..0 = mantissa MSB-first
        uint32_t word = (s << 15) | (exp5 << 10) | mant;

        #pragma unroll
        for (int k = 0; k < 4; ++k) {
            // out-quad index O = 4*base + 64k + lane -> group base+16k+(lane>>2), quad lane&3
            uint32_t w = (uint32_t)__shfl((int)word, 16 * k + srcb, 64);
            f32x4 r;
            r[0] = (float)((w >> (sh3 + 3)) & 1u);
            r[1] = (float)((w >> (sh3 + 2)) & 1u);
            r[2] = (float)((w >> (sh3 + 1)) & 1u);
            r[3] = (float)((w >> (sh3    )) & 1u);
            __builtin_nontemporal_store(r, &out4[4 * base + 64 * k + lane]);
        }
    }
}

extern "C" void kernel_launch(void* const* d_in, const int* in_sizes, int n_in,
                              void* d_out, int out_size, void* d_ws, size_t ws_size,
                              hipStream_t stream)
{
    const f32x4* in4 = (const f32x4*)d_in[0];
    f32x4* out4 = (f32x4*)d_out;
    int n_groups = in_sizes[0] / 8;   // 16,777,216 (multiple of 64)

    // 2048 blocks x 256 threads = 8192 waves; 32 tile-iterations per wave.
    dim3 grid(2048), block(256);
    fp8_to_fp16_bits_kernel<<<grid, block, 0, stream>>>(in4, out4, n_groups);
}